// Round 2
// baseline (844.103 us; speedup 1.0000x reference)
//
#include <hip/hip_runtime.h>

#define BLOCK 256
#define GRID 2048
#define ILP 4   // int4 chunks per thread per loop body = 16 pairs = 32 gathers in flight

// clang ext_vector so __builtin_nontemporal_load works (HIP's int4 is a struct)
typedef int v4i __attribute__((ext_vector_type(4)));

__global__ __launch_bounds__(BLOCK) void dti_pu_loss_kernel(
    const float* __restrict__ R,      // drug_protein_reconstruct
    const float* __restrict__ D,      // drug_protein
    const float* __restrict__ alpha,  // 1 element
    const int* __restrict__ px, const int* __restrict__ py, int npos,
    const int* __restrict__ nx, const int* __restrict__ ny, int nneg,
    float* __restrict__ out)
{
    const int tid    = blockIdx.x * BLOCK + threadIdx.x;
    const int stride = GRID * BLOCK;

    float pos_acc = 0.0f;
    float neg_acc = 0.0f;

    // ---- positive pairs: blocked ILP-4, batched independent gathers ----
    {
        const int n4 = npos >> 2;
        const v4i* px4 = (const v4i*)px;
        const v4i* py4 = (const v4i*)py;
        for (int base = tid * ILP; base < n4; base += stride * ILP) {
            v4i X[ILP], Y[ILP];
            // 1) issue all index loads (non-temporal: stream, never reused)
            #pragma unroll
            for (int k = 0; k < ILP; ++k) {
                if (base + k < n4) {
                    X[k] = __builtin_nontemporal_load(&px4[base + k]);
                    Y[k] = __builtin_nontemporal_load(&py4[base + k]);
                }
            }
            // 2) issue all 32 gathers, then accumulate
            #pragma unroll
            for (int k = 0; k < ILP; ++k) {
                if (base + k < n4) {
                    int o0 = (X[k].x << 13) + Y[k].x;
                    int o1 = (X[k].y << 13) + Y[k].y;
                    int o2 = (X[k].z << 13) + Y[k].z;
                    int o3 = (X[k].w << 13) + Y[k].w;
                    float d0 = R[o0] - D[o0];
                    float d1 = R[o1] - D[o1];
                    float d2 = R[o2] - D[o2];
                    float d3 = R[o3] - D[o3];
                    pos_acc += d0 * d0 + d1 * d1 + d2 * d2 + d3 * d3;
                }
            }
        }
        // scalar tail (empty when npos % 4 == 0)
        for (int i = (n4 << 2) + tid; i < npos; i += stride) {
            int o = (px[i] << 13) + py[i];
            float d = R[o] - D[o];
            pos_acc += d * d;
        }
    }

    // ---- negative pairs: same structure ----
    {
        const int n4 = nneg >> 2;
        const v4i* nx4 = (const v4i*)nx;
        const v4i* ny4 = (const v4i*)ny;
        for (int base = tid * ILP; base < n4; base += stride * ILP) {
            v4i X[ILP], Y[ILP];
            #pragma unroll
            for (int k = 0; k < ILP; ++k) {
                if (base + k < n4) {
                    X[k] = __builtin_nontemporal_load(&nx4[base + k]);
                    Y[k] = __builtin_nontemporal_load(&ny4[base + k]);
                }
            }
            #pragma unroll
            for (int k = 0; k < ILP; ++k) {
                if (base + k < n4) {
                    int o0 = (X[k].x << 13) + Y[k].x;
                    int o1 = (X[k].y << 13) + Y[k].y;
                    int o2 = (X[k].z << 13) + Y[k].z;
                    int o3 = (X[k].w << 13) + Y[k].w;
                    float d0 = R[o0] - D[o0];
                    float d1 = R[o1] - D[o1];
                    float d2 = R[o2] - D[o2];
                    float d3 = R[o3] - D[o3];
                    neg_acc += d0 * d0 + d1 * d1 + d2 * d2 + d3 * d3;
                }
            }
        }
        for (int i = (n4 << 2) + tid; i < nneg; i += stride) {
            int o = (nx[i] << 13) + ny[i];
            float d = R[o] - D[o];
            neg_acc += d * d;
        }
    }

    // ---- combine with alpha (linear => per-thread combine is exact) ----
    const float a = alpha[0];
    float v = pos_acc * ((1.0f - a) * 0.5f) + neg_acc * (a * 0.5f);

    // ---- wave reduce (64 lanes) ----
    #pragma unroll
    for (int off = 32; off > 0; off >>= 1)
        v += __shfl_down(v, off, 64);

    // ---- block reduce via LDS, one atomic per block ----
    __shared__ float sdata[BLOCK / 64];
    const int lane = threadIdx.x & 63;
    const int wave = threadIdx.x >> 6;
    if (lane == 0) sdata[wave] = v;
    __syncthreads();
    if (threadIdx.x == 0) {
        float s = 0.0f;
        #pragma unroll
        for (int w = 0; w < BLOCK / 64; ++w) s += sdata[w];
        atomicAdd(out, s);
    }
}

extern "C" void kernel_launch(void* const* d_in, const int* in_sizes, int n_in,
                              void* d_out, int out_size, void* d_ws, size_t ws_size,
                              hipStream_t stream) {
    const float* R     = (const float*)d_in[0];
    const float* D     = (const float*)d_in[1];
    const float* alpha = (const float*)d_in[2];
    const int*   px    = (const int*)d_in[3];
    const int*   py    = (const int*)d_in[4];
    const int*   nx    = (const int*)d_in[5];
    const int*   ny    = (const int*)d_in[6];
    const int    npos  = in_sizes[3];
    const int    nneg  = in_sizes[5];

    float* out = (float*)d_out;

    // d_out is poisoned with 0xAA before every timed launch — zero it.
    hipMemsetAsync(out, 0, sizeof(float), stream);

    dti_pu_loss_kernel<<<GRID, BLOCK, 0, stream>>>(
        R, D, alpha, px, py, npos, nx, ny, nneg, out);
}

// Round 3
// 708.081 us; speedup vs baseline: 1.1921x; 1.1921x over previous
//
#include <hip/hip_runtime.h>

#define BLOCK 256
#define GRID  2048
#define NBUCK 256           // 32 rows per bucket -> 2 MB (R+D) footprint per bucket
#define PIPT  16            // partition: items per thread per chunk
#define PCHUNK (BLOCK * PIPT)

typedef int v4i __attribute__((ext_vector_type(4)));

__device__ __forceinline__ void block_reduce_out(float pos_acc, float neg_acc,
                                                 const float* alpha, float* out) {
    const float a = alpha[0];
    float v = pos_acc * ((1.0f - a) * 0.5f) + neg_acc * (a * 0.5f);
    #pragma unroll
    for (int off = 32; off > 0; off >>= 1)
        v += __shfl_down(v, off, 64);
    __shared__ float sdata[BLOCK / 64];
    const int lane = threadIdx.x & 63;
    const int wave = threadIdx.x >> 6;
    if (lane == 0) sdata[wave] = v;
    __syncthreads();
    if (threadIdx.x == 0) {
        float s = 0.0f;
        #pragma unroll
        for (int w = 0; w < BLOCK / 64; ++w) s += sdata[w];
        if (s != 0.0f) atomicAdd(out, s);
    }
}

// ---------------- pass 1: bin packed offsets by row-block ----------------
__global__ __launch_bounds__(BLOCK) void partition_kernel(
    const int* __restrict__ px, const int* __restrict__ py, int npos,
    const int* __restrict__ nx, const int* __restrict__ ny, int nneg,
    unsigned* __restrict__ items, unsigned* __restrict__ gcnt, int cap,
    const float* __restrict__ R, const float* __restrict__ D,
    const float* __restrict__ alpha, float* __restrict__ out)
{
    __shared__ unsigned s_cnt[NBUCK];
    __shared__ unsigned s_base[NBUCK];
    __shared__ unsigned s_cur[NBUCK];

    const int tid   = threadIdx.x;
    const int total = npos + nneg;
    const int nchunks = (total + PCHUNK - 1) / PCHUNK;

    float pos_acc = 0.0f, neg_acc = 0.0f;   // overflow-direct path (normally empty)

    for (int c = blockIdx.x; c < nchunks; c += gridDim.x) {
        const int run = c * PCHUNK + tid * PIPT;       // this thread's 16 consecutive items
        const int nval = min(PIPT, max(0, total - run));

        unsigned it[PIPT];
        if (nval == PIPT && run + PIPT <= npos) {
            // pure-positive vector path
            const v4i* x4 = (const v4i*)(px + run);
            const v4i* y4 = (const v4i*)(py + run);
            #pragma unroll
            for (int q = 0; q < PIPT / 4; ++q) {
                v4i xs = x4[q], ys = y4[q];
                it[q*4+0] = ((unsigned)xs.x << 13) | (unsigned)ys.x;
                it[q*4+1] = ((unsigned)xs.y << 13) | (unsigned)ys.y;
                it[q*4+2] = ((unsigned)xs.z << 13) | (unsigned)ys.z;
                it[q*4+3] = ((unsigned)xs.w << 13) | (unsigned)ys.w;
            }
        } else if (nval == PIPT && run >= npos && (((run - npos) & 3) == 0)) {
            // pure-negative vector path
            const int j = run - npos;
            const v4i* x4 = (const v4i*)(nx + j);
            const v4i* y4 = (const v4i*)(ny + j);
            #pragma unroll
            for (int q = 0; q < PIPT / 4; ++q) {
                v4i xs = x4[q], ys = y4[q];
                it[q*4+0] = (((unsigned)xs.x << 13) | (unsigned)ys.x) | (1u << 26);
                it[q*4+1] = (((unsigned)xs.y << 13) | (unsigned)ys.y) | (1u << 26);
                it[q*4+2] = (((unsigned)xs.z << 13) | (unsigned)ys.z) | (1u << 26);
                it[q*4+3] = (((unsigned)xs.w << 13) | (unsigned)ys.w) | (1u << 26);
            }
        } else {
            // boundary/tail scalar path
            for (int k = 0; k < PIPT; ++k) {
                const int gi = run + k;
                if (k < nval) {
                    if (gi < npos) it[k] = ((unsigned)px[gi] << 13) | (unsigned)py[gi];
                    else {
                        const int j = gi - npos;
                        it[k] = (((unsigned)nx[j] << 13) | (unsigned)ny[j]) | (1u << 26);
                    }
                } else it[k] = 0;
            }
        }

        // histogram in LDS
        s_cnt[tid] = 0;
        __syncthreads();
        #pragma unroll
        for (int k = 0; k < PIPT; ++k)
            if (k < nval) atomicAdd(&s_cnt[(it[k] >> 18) & 0xFF], 1u);
        __syncthreads();

        // one global reservation per non-empty bucket
        const unsigned cnt = s_cnt[tid];
        if (cnt) s_base[tid] = atomicAdd(&gcnt[tid], cnt);
        s_cur[tid] = 0;
        __syncthreads();

        // scatter to reserved slots (runs are line-dense: ~16 items/bucket/chunk)
        #pragma unroll
        for (int k = 0; k < PIPT; ++k) {
            if (k < nval) {
                const unsigned b = (it[k] >> 18) & 0xFF;
                const unsigned p = atomicAdd(&s_cur[b], 1u);
                const unsigned gpos = s_base[b] + p;
                if (gpos < (unsigned)cap) {
                    items[(size_t)b * cap + gpos] = it[k];
                } else {
                    // capacity overflow: process directly (correctness guarantee)
                    const unsigned o = it[k] & 0x3FFFFFFu;
                    const float d = R[o] - D[o];
                    if (it[k] >> 26) neg_acc += d * d; else pos_acc += d * d;
                }
            }
        }
        __syncthreads();
    }

    block_reduce_out(pos_acc, neg_acc, alpha, out);
}

// ---------------- pass 2: XCD-affine in-phase bucket gather ----------------
__global__ __launch_bounds__(BLOCK) void gather_kernel(
    const float* __restrict__ R, const float* __restrict__ D,
    const float* __restrict__ alpha,
    const unsigned* __restrict__ items, const unsigned* __restrict__ gcnt,
    int cap, float* __restrict__ out)
{
    const int xcd = blockIdx.x & 7;       // assumed round-robin block->XCD mapping
    const int g   = blockIdx.x >> 3;      // 0..255 team index inside XCD group
    const unsigned team_stride = (GRID / 8) * BLOCK;   // 65536 threads per XCD group

    float pos_acc = 0.0f, neg_acc = 0.0f;

    // all blocks of an XCD group walk the same 32-bucket sequence in phase:
    // active footprint per XCD ~= 1-3 buckets * 2 MB vs 4 MB L2.
    for (int bi = 0; bi < NBUCK / 8; ++bi) {
        const int b = bi * 8 + xcd;
        const unsigned n = min(gcnt[b], (unsigned)cap);
        const unsigned* ib = items + (size_t)b * cap;
        for (unsigned i = (unsigned)g * BLOCK + threadIdx.x; i < n; i += team_stride) {
            const unsigned it = ib[i];
            const unsigned o = it & 0x3FFFFFFu;
            const float d = R[o] - D[o];
            if (it >> 26) neg_acc += d * d; else pos_acc += d * d;
        }
    }

    block_reduce_out(pos_acc, neg_acc, alpha, out);
}

// ---------------- fallback: proven direct kernel (round-0) ----------------
__global__ __launch_bounds__(BLOCK) void dti_direct_kernel(
    const float* __restrict__ R, const float* __restrict__ D,
    const float* __restrict__ alpha,
    const int* __restrict__ px, const int* __restrict__ py, int npos,
    const int* __restrict__ nx, const int* __restrict__ ny, int nneg,
    float* __restrict__ out)
{
    const int tid = blockIdx.x * BLOCK + threadIdx.x;
    const int stride = gridDim.x * BLOCK;
    float pos_acc = 0.0f, neg_acc = 0.0f;
    {
        const int n4 = npos >> 2;
        const v4i* px4 = (const v4i*)px;
        const v4i* py4 = (const v4i*)py;
        for (int i = tid; i < n4; i += stride) {
            v4i xs = px4[i], ys = py4[i];
            int o0 = (xs.x << 13) + ys.x, o1 = (xs.y << 13) + ys.y;
            int o2 = (xs.z << 13) + ys.z, o3 = (xs.w << 13) + ys.w;
            float d0 = R[o0]-D[o0], d1 = R[o1]-D[o1], d2 = R[o2]-D[o2], d3 = R[o3]-D[o3];
            pos_acc += d0*d0 + d1*d1 + d2*d2 + d3*d3;
        }
        for (int i = (n4 << 2) + tid; i < npos; i += stride) {
            int o = (px[i] << 13) + py[i];
            float d = R[o] - D[o];
            pos_acc += d * d;
        }
    }
    {
        const int n4 = nneg >> 2;
        const v4i* nx4 = (const v4i*)nx;
        const v4i* ny4 = (const v4i*)ny;
        for (int i = tid; i < n4; i += stride) {
            v4i xs = nx4[i], ys = ny4[i];
            int o0 = (xs.x << 13) + ys.x, o1 = (xs.y << 13) + ys.y;
            int o2 = (xs.z << 13) + ys.z, o3 = (xs.w << 13) + ys.w;
            float d0 = R[o0]-D[o0], d1 = R[o1]-D[o1], d2 = R[o2]-D[o2], d3 = R[o3]-D[o3];
            neg_acc += d0*d0 + d1*d1 + d2*d2 + d3*d3;
        }
        for (int i = (n4 << 2) + tid; i < nneg; i += stride) {
            int o = (nx[i] << 13) + ny[i];
            float d = R[o] - D[o];
            neg_acc += d * d;
        }
    }
    block_reduce_out(pos_acc, neg_acc, alpha, out);
}

extern "C" void kernel_launch(void* const* d_in, const int* in_sizes, int n_in,
                              void* d_out, int out_size, void* d_ws, size_t ws_size,
                              hipStream_t stream) {
    const float* R     = (const float*)d_in[0];
    const float* D     = (const float*)d_in[1];
    const float* alpha = (const float*)d_in[2];
    const int*   px    = (const int*)d_in[3];
    const int*   py    = (const int*)d_in[4];
    const int*   nx    = (const int*)d_in[5];
    const int*   ny    = (const int*)d_in[6];
    const int    npos  = in_sizes[3];
    const int    nneg  = in_sizes[5];
    const int    total = npos + nneg;

    float* out = (float*)d_out;
    hipMemsetAsync(out, 0, sizeof(float), stream);   // d_out poisoned before launch

    // bucket capacity: mean + 25% + 1024 (>>10 sigma for uniform draws)
    const int cap = total / NBUCK + total / (NBUCK * 4) + 1024;
    const size_t need = (size_t)NBUCK * cap * sizeof(unsigned) + NBUCK * sizeof(unsigned);

    if (d_ws != nullptr && ws_size >= need) {
        unsigned* items = (unsigned*)d_ws;
        unsigned* gcnt  = items + (size_t)NBUCK * cap;
        hipMemsetAsync(gcnt, 0, NBUCK * sizeof(unsigned), stream);
        partition_kernel<<<GRID, BLOCK, 0, stream>>>(
            px, py, npos, nx, ny, nneg, items, gcnt, cap, R, D, alpha, out);
        gather_kernel<<<GRID, BLOCK, 0, stream>>>(
            R, D, alpha, items, gcnt, cap, out);
    } else {
        dti_direct_kernel<<<GRID, BLOCK, 0, stream>>>(
            R, D, alpha, px, py, npos, nx, ny, nneg, out);
    }
}